// Round 5
// baseline (1108.869 us; speedup 1.0000x reference)
//
#include <hip/hip_runtime.h>

// ---------------------------------------------------------------------------
// Problem: B=8, R=128, H=W=4096
//   C    = alpha*I + 2*gamma * N @ N^T        [128x128], SPD -> Cinv symmetric
//   out  = 2*gamma * (Ak_L @ N^T) @ Cinv      (uses Cinv symmetry)
// Pipeline (4 launches):
//   k_gram   : Gpart[b][ks] = partial N*N^T (bf16 MFMA) + writes Nbf = bf16(N)
//   k_inv    : C = alpha*I + 2g*sum(Gpart); 1024-thr in-place Gauss-Jordan
//   k_angemm : AN = A(fp32->bf16) @ Nbf^T  (512MB stream)
//              v3: 32x128 tile, 1024 blocks, 43.5KB LDS, launch_bounds(256,3)
//              -> 3 blocks/CU resident (12 waves/CU, +50% TLP vs v2).
//              2-deep x/y reg prefetch (A+B), LDS dbuf, raw s_barrier,
//              lgkmcnt(0)-only pre-barrier (no vmcnt drain).
//   k_final  : out = 2g * AN @ Cinv, fp32 VALU (Cinv fp32 in LDS)
// (Round-4 resubmission: round-3 bench was an infra failure, no measurement.)
// ---------------------------------------------------------------------------

typedef __attribute__((ext_vector_type(8))) short bf16x8;
typedef __attribute__((ext_vector_type(4))) float f32x4;
typedef __attribute__((ext_vector_type(4))) unsigned int u32x4;

#define MFMA16(a, b, c) __builtin_amdgcn_mfma_f32_16x16x32_bf16((a), (b), (c), 0, 0, 0)
#define NSPLIT 8
#define PAD 68  // shorts; 136B row stride -> 2-bank shift/row, 2-way worst (free)

__device__ __forceinline__ unsigned short f2bf(float f) {
  union { float f; unsigned u; } v; v.f = f;
  unsigned u = v.u;
  return (unsigned short)((u + 0x7FFFu + ((u >> 16) & 1u)) >> 16);  // RNE
}
__device__ __forceinline__ unsigned pack2(float x, float y) {
  return (unsigned)f2bf(x) | ((unsigned)f2bf(y) << 16);
}

// ---------------------------------------------------------------------------
// Kernel 1: Gram partials + Nbf cast. grid (NSPLIT=8, 8 batch), 256 thr.
// ---------------------------------------------------------------------------
__global__ __launch_bounds__(256) void k_gram(const float* __restrict__ N,
                                              float* __restrict__ Gpart,
                                              unsigned short* __restrict__ Nbf) {
  __attribute__((aligned(16))) __shared__ unsigned short lds[128 * 72];
  int ks = blockIdx.x, b = blockIdx.y;
  const float* Nb = N + (size_t)b * 524288 + ks * 512;
  int t = threadIdx.x;
  int wave = t >> 6, lane = t & 63, quad = lane >> 4, l16 = lane & 15;
  f32x4 acc[2][8];
#pragma unroll
  for (int i = 0; i < 2; i++)
#pragma unroll
    for (int j = 0; j < 8; j++) acc[i][j] = (f32x4){0.f, 0.f, 0.f, 0.f};
  int srow = t >> 1, shalf = t & 1;
  const float* srcb = Nb + (size_t)srow * 4096 + shalf * 32;
  unsigned short* dptr = lds + srow * 72 + shalf * 32;
  unsigned short* nbb = Nbf + (size_t)b * 524288 + (size_t)srow * 4096 + ks * 512 + shalf * 32;
  for (int it = 0; it < 8; ++it) {
    u32x4 pk0, pk1;
    {
      f32x4 v0 = *(const f32x4*)(srcb + it * 64 + 0);
      f32x4 v1 = *(const f32x4*)(srcb + it * 64 + 4);
      f32x4 v2 = *(const f32x4*)(srcb + it * 64 + 8);
      f32x4 v3 = *(const f32x4*)(srcb + it * 64 + 12);
      pk0[0] = pack2(v0[0], v0[1]); pk0[1] = pack2(v0[2], v0[3]);
      pk0[2] = pack2(v1[0], v1[1]); pk0[3] = pack2(v1[2], v1[3]);
      pk1[0] = pack2(v2[0], v2[1]); pk1[1] = pack2(v2[2], v2[3]);
      pk1[2] = pack2(v3[0], v3[1]); pk1[3] = pack2(v3[2], v3[3]);
    }
    u32x4 pk2, pk3;
    {
      f32x4 v0 = *(const f32x4*)(srcb + it * 64 + 16);
      f32x4 v1 = *(const f32x4*)(srcb + it * 64 + 20);
      f32x4 v2 = *(const f32x4*)(srcb + it * 64 + 24);
      f32x4 v3 = *(const f32x4*)(srcb + it * 64 + 28);
      pk2[0] = pack2(v0[0], v0[1]); pk2[1] = pack2(v0[2], v0[3]);
      pk2[2] = pack2(v1[0], v1[1]); pk2[3] = pack2(v1[2], v1[3]);
      pk3[0] = pack2(v2[0], v2[1]); pk3[1] = pack2(v2[2], v2[3]);
      pk3[2] = pack2(v3[0], v3[1]); pk3[3] = pack2(v3[2], v3[3]);
    }
    // bf16 copy of N (row-major), reused by k_angemm as the B operand
    *(u32x4*)(nbb + it * 64 + 0) = pk0;
    *(u32x4*)(nbb + it * 64 + 8) = pk1;
    *(u32x4*)(nbb + it * 64 + 16) = pk2;
    *(u32x4*)(nbb + it * 64 + 24) = pk3;
    __syncthreads();
    *(u32x4*)(dptr + 0) = pk0;
    *(u32x4*)(dptr + 8) = pk1;
    *(u32x4*)(dptr + 16) = pk2;
    *(u32x4*)(dptr + 24) = pk3;
    __syncthreads();
    bf16x8 af[2][2], bfv[8][2];
#pragma unroll
    for (int mt = 0; mt < 2; mt++)
#pragma unroll
      for (int kk = 0; kk < 2; kk++)
        af[mt][kk] = *(const bf16x8*)(lds + (wave * 32 + mt * 16 + l16) * 72 + (kk * 4 + quad) * 8);
#pragma unroll
    for (int nt = 0; nt < 8; nt++)
#pragma unroll
      for (int kk = 0; kk < 2; kk++)
        bfv[nt][kk] = *(const bf16x8*)(lds + (nt * 16 + l16) * 72 + (kk * 4 + quad) * 8);
#pragma unroll
    for (int mt = 0; mt < 2; mt++)
#pragma unroll
      for (int nt = 0; nt < 8; nt++)
#pragma unroll
        for (int kk = 0; kk < 2; kk++)
          acc[mt][nt] = MFMA16(af[mt][kk], bfv[nt][kk], acc[mt][nt]);
  }
  float* Gp = Gpart + ((size_t)(b * NSPLIT + ks) << 14);
#pragma unroll
  for (int mt = 0; mt < 2; mt++)
#pragma unroll
    for (int nt = 0; nt < 8; nt++)
#pragma unroll
      for (int rg = 0; rg < 4; rg++) {
        int row = wave * 32 + mt * 16 + quad * 4 + rg;
        int col = nt * 16 + l16;
        Gp[row * 128 + col] = acc[mt][nt][rg];
      }
}

// ---------------------------------------------------------------------------
// Kernel 2: in-place Gauss-Jordan inverse of C = alpha*I + 2g*sum(Gpart).
// grid (8), 1024 thr. Thread (rb=t>>5, cg=t&31) owns 4 rows x 4 cols.
// ONE barrier/step, parity double-buffered pivot row/col. (proven)
// ---------------------------------------------------------------------------
__global__ __launch_bounds__(1024) void k_inv(const float* __restrict__ Gpart,
                                              const float* __restrict__ alpha,
                                              const float* __restrict__ gamma,
                                              float* __restrict__ Cinv) {
  __attribute__((aligned(16))) __shared__ float Cs[16384];
  __attribute__((aligned(16))) __shared__ float mcol[2][128];
  __attribute__((aligned(16))) __shared__ float pivrow[2][128];
  int b = blockIdx.x;
  int t = threadIdx.x;
  const float* Gp = Gpart + ((size_t)b * NSPLIT << 14);
#pragma unroll
  for (int c = 0; c < 4; c++) {
    int off = c * 4096 + t * 4;
    f32x4 s = (f32x4){0.f, 0.f, 0.f, 0.f};
#pragma unroll
    for (int ks = 0; ks < NSPLIT; ks++) s += *(const f32x4*)(Gp + ks * 16384 + off);
    *(f32x4*)(Cs + off) = s;
  }
  __syncthreads();
  int cg = t & 31, rb = t >> 5;  // cg fastest -> coalesced epilogue
  float al = alpha[b], ga2 = 2.f * gamma[b];
  float a[4][4];
#pragma unroll
  for (int i = 0; i < 4; i++) {
    int r = rb * 4 + i;
    f32x4 v = *(const f32x4*)(Cs + r * 128 + cg * 4);
#pragma unroll
    for (int j = 0; j < 4; j++) {
      int c = cg * 4 + j;
      a[i][j] = ga2 * v[j] + ((r == c) ? al : 0.f);
    }
  }
  for (int p = 0; p < 128; ++p) {
    int pb = p & 1;
    int cgp = p >> 2, jp = p & 3;
    int rbp = p >> 2, ip = p & 3;
    if (cg == cgp) {  // capture column p (own regs, pre-update)
      f32x4 mv;
#pragma unroll
      for (int i = 0; i < 4; i++)
        mv[i] = (jp & 2) ? ((jp & 1) ? a[i][3] : a[i][2]) : ((jp & 1) ? a[i][1] : a[i][0]);
      *(f32x4*)&mcol[pb][rb * 4] = mv;
    }
    if (rb == rbp) {  // capture row p (unnormalized)
      f32x4 pv;
#pragma unroll
      for (int j = 0; j < 4; j++)
        pv[j] = (ip & 2) ? ((ip & 1) ? a[3][j] : a[2][j]) : ((ip & 1) ? a[1][j] : a[0][j]);
      *(f32x4*)&pivrow[pb][cg * 4] = pv;
    }
    __syncthreads();
    float invd = 1.0f / mcol[pb][p];  // mcol[p] == a[p][p]
    f32x4 mc = *(const f32x4*)&mcol[pb][rb * 4];
    f32x4 pr = *(const f32x4*)&pivrow[pb][cg * 4];
#pragma unroll
    for (int i = 0; i < 4; i++) {
      int r = rb * 4 + i;
      float mi = mc[i] * invd;
#pragma unroll
      for (int j = 0; j < 4; j++) {
        int c = cg * 4 + j;
        float v = a[i][j] - mi * pr[j];
        if (c == p) v = -mi;
        if (r == p) v = pr[j] * invd;
        if (r == p && c == p) v = invd;
        a[i][j] = v;
      }
    }
    // no second barrier: next capture writes the OTHER parity buffer and
    // reads only the capturing thread's own (in-order updated) registers.
  }
  float* dst = Cinv + ((size_t)b << 14);
#pragma unroll
  for (int i = 0; i < 4; i++) {
    int r = rb * 4 + i;
    *(f32x4*)(dst + r * 128 + cg * 4) = (f32x4){a[i][0], a[i][1], a[i][2], a[i][3]};
  }
}

// ---------------------------------------------------------------------------
// Kernel 3: AN[b][h][r] = sum_w A[b][h][w] * Nbf[b][r][w]
// v3: grid 1024 1D: b = blk&7 (XCD-swizzle), mtile = blk>>3 (0..127).
// 256 thr (4 waves), tile 32(h) x 128(r), BK=64, 64 K-steps.
// LDS 43.5KB + launch_bounds(256,3) -> 3 blocks/CU resident (12 waves/CU).
// 2-deep x/y register prefetch for A and B, LDS dbuf, one raw s_barrier/step,
// lgkmcnt(0)-only before it (vmcnt stays counted at the pack site).
// ---------------------------------------------------------------------------
__device__ __forceinline__ void an_step(
    f32x4& A0, f32x4& A1,
    u32x4& B0, u32x4& B1, u32x4& B2, u32x4& B3,
    unsigned short* adst, unsigned short* bdst,
    const unsigned short* lap, const unsigned short* lbp,
    const float* asrc, const unsigned short* bsrc,
    int it, int wm, int wr, int quad, int l16,
    f32x4 (&acc)[4]) {
  u32x4 pa;  // pack A fp32->bf16 (counted vmcnt wait lands here)
  pa[0] = pack2(A0[0], A0[1]); pa[1] = pack2(A0[2], A0[3]);
  pa[2] = pack2(A1[0], A1[1]); pa[3] = pack2(A1[2], A1[3]);
  *(u32x4*)(adst) = pa;
  *(u32x4*)(bdst + 0) = B0;
  *(u32x4*)(bdst + 8) = B1;
  *(u32x4*)(bdst + 16) = B2;
  *(u32x4*)(bdst + 24) = B3;
  asm volatile("s_waitcnt lgkmcnt(0)" ::: "memory");  // LDS visible; vmcnt untouched
  __builtin_amdgcn_s_barrier();
  __builtin_amdgcn_sched_barrier(0);
  if (it + 2 < 64) {  // refill this set for step it+2
    int k0 = (it + 2) * 64;
    A0 = *(const f32x4*)(asrc + k0 + 0);
    A1 = *(const f32x4*)(asrc + k0 + 4);
    B0 = *(const u32x4*)(bsrc + k0 + 0);
    B1 = *(const u32x4*)(bsrc + k0 + 8);
    B2 = *(const u32x4*)(bsrc + k0 + 16);
    B3 = *(const u32x4*)(bsrc + k0 + 24);
  }
  bf16x8 af[2], bfv[4][2];
#pragma unroll
  for (int kk = 0; kk < 2; kk++)
    af[kk] = *(const bf16x8*)(lap + (wm * 16 + l16) * PAD + (kk * 4 + quad) * 8);
#pragma unroll
  for (int rt = 0; rt < 4; rt++)
#pragma unroll
    for (int kk = 0; kk < 2; kk++)
      bfv[rt][kk] = *(const bf16x8*)(lbp + (wr * 64 + rt * 16 + l16) * PAD + (kk * 4 + quad) * 8);
#pragma unroll
  for (int rt = 0; rt < 4; rt++)
#pragma unroll
    for (int kk = 0; kk < 2; kk++)
      acc[rt] = MFMA16(af[kk], bfv[rt][kk], acc[rt]);
}

__global__ __launch_bounds__(256, 3) void k_angemm(const float* __restrict__ A,
                                                   const unsigned short* __restrict__ Nbf,
                                                   float* __restrict__ ANf) {
  __attribute__((aligned(16))) __shared__ unsigned short la[2][32 * PAD];
  __attribute__((aligned(16))) __shared__ unsigned short lb[2][128 * PAD];
  int blk = blockIdx.x;
  int b = blk & 7, mtile = blk >> 3;
  const float* Ab = A + (size_t)b * 16777216 + (size_t)mtile * 32 * 4096;
  const unsigned short* Mb = Nbf + (size_t)b * 524288;
  int t = threadIdx.x, wave = t >> 6, lane = t & 63, quad = lane >> 4, l16 = lane & 15;
  int wm = wave >> 1, wr = wave & 1;  // wave: 16 h-rows x 64 r-cols
  f32x4 acc[4];
#pragma unroll
  for (int j = 0; j < 4; j++) acc[j] = (f32x4){0.f, 0.f, 0.f, 0.f};
  int arow = t >> 3, aq = t & 7;   // A tile 32 x 64 fp32: 8 floats/thread/step
  int brow = t >> 1, bhalf = t & 1;  // B tile 128 x 64 bf16: 32 shorts/thread
  const float* asrc = Ab + (size_t)arow * 4096 + aq * 8;
  const unsigned short* bsrc = Mb + (size_t)brow * 4096 + bhalf * 32;
  unsigned short* adst0 = &la[0][arow * PAD + aq * 8];
  unsigned short* adst1 = &la[1][arow * PAD + aq * 8];
  unsigned short* bdst0 = &lb[0][brow * PAD + bhalf * 32];
  unsigned short* bdst1 = &lb[1][brow * PAD + bhalf * 32];
  // prologue: issue step 0 into set x, step 1 into set y
  f32x4 xa0 = *(const f32x4*)(asrc + 0);
  f32x4 xa1 = *(const f32x4*)(asrc + 4);
  u32x4 xb0 = *(const u32x4*)(bsrc + 0);
  u32x4 xb1 = *(const u32x4*)(bsrc + 8);
  u32x4 xb2 = *(const u32x4*)(bsrc + 16);
  u32x4 xb3 = *(const u32x4*)(bsrc + 24);
  f32x4 ya0 = *(const f32x4*)(asrc + 64);
  f32x4 ya1 = *(const f32x4*)(asrc + 68);
  u32x4 yb0 = *(const u32x4*)(bsrc + 64);
  u32x4 yb1 = *(const u32x4*)(bsrc + 72);
  u32x4 yb2 = *(const u32x4*)(bsrc + 80);
  u32x4 yb3 = *(const u32x4*)(bsrc + 88);
  for (int itp = 0; itp < 32; ++itp) {
    an_step(xa0, xa1, xb0, xb1, xb2, xb3, adst0, bdst0, &la[0][0], &lb[0][0],
            asrc, bsrc, 2 * itp, wm, wr, quad, l16, acc);
    an_step(ya0, ya1, yb0, yb1, yb2, yb3, adst1, bdst1, &la[1][0], &lb[1][0],
            asrc, bsrc, 2 * itp + 1, wm, wr, quad, l16, acc);
  }
  float* ob = ANf + (size_t)b * 524288 + (size_t)mtile * 32 * 128;
#pragma unroll
  for (int rt = 0; rt < 4; rt++)
#pragma unroll
    for (int rg = 0; rg < 4; rg++) {
      int h = wm * 16 + quad * 4 + rg;
      int r = wr * 64 + rt * 16 + l16;
      ob[h * 128 + r] = acc[rt][rg];
    }
}

// ---------------------------------------------------------------------------
// Kernel 4: out[b][h][s] = 2g * sum_r AN[h][r] * Cinv[r][s]   (fp32 VALU)
// grid 512 (64 htiles x 8 b), 256 thr. Cinv fp32 in LDS.
// ---------------------------------------------------------------------------
__global__ __launch_bounds__(256) void k_final(const float* __restrict__ AN,
                                               const float* __restrict__ Cinv,
                                               const float* __restrict__ gamma,
                                               float* __restrict__ out) {
  __attribute__((aligned(16))) __shared__ float Cs[16384];  // 64KB, [r][s]
  int blk = blockIdx.x;
  int b = blk & 7, mtile = blk >> 3;
  const float* Cb = Cinv + ((size_t)b << 14);
  int t = threadIdx.x;
#pragma unroll
  for (int c = 0; c < 4; c++) {
    int off = c * 4096 + t * 16;
#pragma unroll
    for (int q = 0; q < 4; q++)
      *(f32x4*)(Cs + off + q * 4) = *(const f32x4*)(Cb + off + q * 4);
  }
  __syncthreads();
  int sg = t >> 4, hg = t & 15;  // thread: 4 h-rows (hg*4..) x 8 s-cols (sg*8..)
  const float* ANb = AN + (size_t)b * 524288 + (size_t)mtile * 64 * 128;
  f32x4 acc[4][2];
#pragma unroll
  for (int i = 0; i < 4; i++) {
    acc[i][0] = (f32x4){0.f, 0.f, 0.f, 0.f};
    acc[i][1] = (f32x4){0.f, 0.f, 0.f, 0.f};
  }
  for (int r0 = 0; r0 < 128; r0 += 16) {
    f32x4 av[4][4];
#pragma unroll
    for (int i = 0; i < 4; i++)
#pragma unroll
      for (int k4 = 0; k4 < 4; k4++)
        av[i][k4] = *(const f32x4*)(ANb + (hg * 4 + i) * 128 + r0 + k4 * 4);
#pragma unroll
    for (int rr = 0; rr < 16; rr++) {
      f32x4 c0 = *(const f32x4*)(Cs + (r0 + rr) * 128 + sg * 8);
      f32x4 c1 = *(const f32x4*)(Cs + (r0 + rr) * 128 + sg * 8 + 4);
#pragma unroll
      for (int i = 0; i < 4; i++) {
        float aval = av[i][rr >> 2][rr & 3];
        acc[i][0] += aval * c0;
        acc[i][1] += aval * c1;
      }
    }
  }
  float ga2 = 2.f * gamma[b];
  float* ob = out + (size_t)b * 524288 + (size_t)mtile * 64 * 128;
#pragma unroll
  for (int i = 0; i < 4; i++) {
    *(f32x4*)(ob + (hg * 4 + i) * 128 + sg * 8) = ga2 * acc[i][0];
    *(f32x4*)(ob + (hg * 4 + i) * 128 + sg * 8 + 4) = ga2 * acc[i][1];
  }
}

// ---------------------------------------------------------------------------
extern "C" void kernel_launch(void* const* d_in, const int* in_sizes, int n_in,
                              void* d_out, int out_size, void* d_ws, size_t ws_size,
                              hipStream_t stream) {
  const float* N = (const float*)d_in[0];
  const float* Ak = (const float*)d_in[1];
  const float* alpha = (const float*)d_in[2];
  const float* gamma = (const float*)d_in[3];
  float* out = (float*)d_out;
  char* ws = (char*)d_ws;
  // workspace layout (~28.5 MB)
  unsigned short* Nbf = (unsigned short*)(ws);             // 8 MB : bf16(N)
  float* Gpart = (float*)(ws + 8388608);                   // 4 MB : gram partials
  float* Cinv = (float*)(ws + 12582912);                   // 512KB: fp32 inverses
  float* ANf = (float*)(ws + 13107200);                    // 16 MB: A@N^T fp32

  k_gram<<<dim3(NSPLIT, 8), 256, 0, stream>>>(N, Gpart, Nbf);
  k_inv<<<dim3(8), 1024, 0, stream>>>(Gpart, alpha, gamma, Cinv);
  k_angemm<<<dim3(1024), 256, 0, stream>>>(Ak, Nbf, ANf);
  k_final<<<dim3(512), 256, 0, stream>>>(ANf, Cinv, gamma, out);
}